// Round 16
// baseline (34.432 us; speedup 1.0000x reference)
//
#include <hip/hip_runtime.h>
#include <hip/hip_fp16.h>

typedef _Float16 f16x8 __attribute__((ext_vector_type(8)));
typedef float f32x4 __attribute__((ext_vector_type(4)));
typedef float f32x16 __attribute__((ext_vector_type(16)));

#define N_PTS 32768
#define ROWS 64         // rows per block

// ---- prep: repack W2 (fp32 [4096][64]) + b2 into f16 fragments for
// v_mfma_f32_32x32x16_f16 (R13-proven layout). One block per chunk c.
//   wsB[c*4096 + t*8 + j], t = ns*256 + kt*64 + lane:
//     = Wf[c*64 + kt*16 + (lane>>5)*8 + j][ns*32 + (lane&31)]
__global__ __launch_bounds__(256) void prep_kernel(
    const float* __restrict__ W2, const float* __restrict__ b2,
    _Float16* __restrict__ wsB) {
  __shared__ _Float16 w_lds[64][72];
  const int c   = blockIdx.x;
  const int tid = threadIdx.x;
  {  // coalesced load: 16 consecutive f32 -> f16 -> LDS
    const float* src = (c < 64) ? (W2 + c * 4096 + tid * 16) : (b2 + tid * 16);
    int kl = tid >> 2, o = (tid & 3) * 16;
    f16x8 v0, v1;
    #pragma unroll
    for (int j = 0; j < 8; ++j) {
      v0[j] = (_Float16)src[j];
      v1[j] = (_Float16)src[8 + j];
    }
    *(f16x8*)(&w_lds[kl][o])     = v0;
    *(f16x8*)(&w_lds[kl][o + 8]) = v1;
  }
  __syncthreads();
  #pragma unroll
  for (int u = 0; u < 2; ++u) {
    int t = tid + u * 256;           // dest frag-slot within c: 0..511
    int lane = t & 63;
    int kt   = (t >> 6) & 3;
    int ns   = t >> 8;
    int klbase = kt * 16 + ((lane >> 5) << 3);
    int o      = ns * 32 + (lane & 31);
    f16x8 v;
    #pragma unroll
    for (int j = 0; j < 8; ++j) v[j] = w_lds[klbase + j][o];
    *(f16x8*)(wsB + c * 4096 + t * 8) = v;
  }
}

// ---- main: 32x32x16, wave = 32 rows x FULL N, 2-way K-split ----
// 512 blocks x 256 threads (4 waves = 2 mg x 2 ks), 2 blocks/CU. Per chunk
// per wave: 16 pk_mul (h is per-lane SCALAR: A rows = lane&31) + 8 MFMA
// (kt-outer: alternates acc[0]/acc[1], dep-distance 2). Issue: 96 cyc/chunk
// per 32 rows = 192/64 rows vs R12's 219. No barriers in K-loop.
__global__ __launch_bounds__(256) void main_kernel(
    const float* __restrict__ x, const float* __restrict__ gridp,
    const float* __restrict__ W1, const float* __restrict__ b1,
    const _Float16* __restrict__ wsB, float* __restrict__ out) {

  __shared__ _Float16 h_t[2][ROWS][36];   // 9216 B: h_t[par][row][p] = h[row][par+2p]
  __shared__ float part[2][ROWS][68];     // 34816 B; total 44032 -> 2 blocks/CU

  const int tid  = threadIdx.x;
  const int lane = tid & 63;
  const int wave = tid >> 6;
  const int mg   = wave >> 1;        // row half: rows [32mg, 32mg+32)
  const int ks   = wave & 1;         // chunk parity: c = ks + 2p
  const int rowblk = blockIdx.x * ROWS;
  const int r31 = lane & 31;
  const int hi  = lane >> 5;

  // phase 0: issue x gathers early (prologue-only; R6 proved non-factor).
  // xf[kt] = x[rowblk + 32mg + r31][kt*16 + hi*8 .. +8]
  const float* xr = x + (rowblk + mg * 32 + r31) * 64 + hi * 8;
  f32x4 xa[4], xb[4];
  #pragma unroll
  for (int kt = 0; kt < 4; ++kt) {
    xa[kt] = *(const f32x4*)(xr + kt * 16);
    xb[kt] = *(const f32x4*)(xr + kt * 16 + 4);
  }

  // phase 1: h = gelu(grid@W1+b1), tanh-form. Thread (row = tid>>2, sub):
  // k = par + 2*(sub*8 + qq) -> h_t[par][row][sub*8+qq]. Parity-packed so
  // each wave later vector-loads its 32 h values (4x b128).
  {
    int row = tid >> 2, sub = tid & 3;
    int r = rowblk + row;
    float g0 = gridp[r * 3 + 0], g1 = gridp[r * 3 + 1], g2 = gridp[r * 3 + 2];
    #pragma unroll
    for (int par = 0; par < 2; ++par) {
      f16x8 hv;
      #pragma unroll
      for (int qq = 0; qq < 8; ++qq) {
        int k = par + 2 * (sub * 8 + qq);
        float v = g0 * W1[k] + g1 * W1[64 + k] + g2 * W1[128 + k] + b1[k];
        float v2 = v * v;
        float u  = v * fmaf(0.044715f, v2, 1.0f);
        float e  = __builtin_amdgcn_exp2f(u * 2.3022084f);
        float rr = e + 1.0f;
        float inv;
        asm("v_rcp_f32 %0, %1" : "=v"(inv) : "v"(rr));
        hv[qq] = (_Float16)(v * (1.0f - inv));
      }
      *(f16x8*)(&h_t[par][row][sub * 8]) = hv;
    }
  }

  // convert x to f16 fragments while h finishes elsewhere
  f16x8 xf[4];
  #pragma unroll
  for (int kt = 0; kt < 4; ++kt) {
    f16x8 v;
    #pragma unroll
    for (int j = 0; j < 4; ++j) {
      v[j]     = (_Float16)xa[kt][j];
      v[4 + j] = (_Float16)xb[kt][j];
    }
    xf[kt] = v;
  }
  __syncthreads();

  const _Float16* bp = wsB + lane * 8;
  auto LOADB = [&](f16x8* b, int c) {     // full chunk: 8 frags (all ns, kt)
    #pragma unroll
    for (int q = 0; q < 8; ++q)
      b[q] = *(const f16x8*)(bp + (c * 8 + q) * 512);
  };

  // issue first B batches, then pull h into registers
  f16x8 bA[8], bB[8], bC[8];
  LOADB(bA, ks);
  LOADB(bB, ks + 2);
  LOADB(bC, ks + 4);

  // hreg[i][j] = h[32mg + r31][c = ks + 2*(8i+j)]  (per-lane scalar per chunk)
  f16x8 hreg[4];
  #pragma unroll
  for (int i = 0; i < 4; ++i)
    hreg[i] = *(const f16x8*)(&h_t[ks][mg * 32 + r31][i * 8]);

  f32x16 acc[2];
  #pragma unroll
  for (int ns = 0; ns < 2; ++ns)
    #pragma unroll
    for (int i = 0; i < 16; ++i) acc[ns][i] = 0.f;

  auto COMPUTE = [&](const f16x8* b, int p) {   // p static after unroll
    _Float16 hh = hreg[p >> 3][p & 7];
    f16x8 hs = {hh, hh, hh, hh, hh, hh, hh, hh};
    f16x8 a0 = xf[0] * hs, a1 = xf[1] * hs, a2 = xf[2] * hs, a3 = xf[3] * hs;
    // kt-outer: acc[0]/acc[1] alternate -> dependent-MFMA distance 2
    acc[0] = __builtin_amdgcn_mfma_f32_32x32x16_f16(a0, b[0], acc[0], 0, 0, 0);
    acc[1] = __builtin_amdgcn_mfma_f32_32x32x16_f16(a0, b[4], acc[1], 0, 0, 0);
    acc[0] = __builtin_amdgcn_mfma_f32_32x32x16_f16(a1, b[1], acc[0], 0, 0, 0);
    acc[1] = __builtin_amdgcn_mfma_f32_32x32x16_f16(a1, b[5], acc[1], 0, 0, 0);
    acc[0] = __builtin_amdgcn_mfma_f32_32x32x16_f16(a2, b[2], acc[0], 0, 0, 0);
    acc[1] = __builtin_amdgcn_mfma_f32_32x32x16_f16(a2, b[6], acc[1], 0, 0, 0);
    acc[0] = __builtin_amdgcn_mfma_f32_32x32x16_f16(a3, b[3], acc[0], 0, 0, 0);
    acc[1] = __builtin_amdgcn_mfma_f32_32x32x16_f16(a3, b[7], acc[1], 0, 0, 0);
  };
  auto COMPUTE_BIAS = [&](const f16x8* b) {     // h == 1: A = xf directly
    acc[0] = __builtin_amdgcn_mfma_f32_32x32x16_f16(xf[0], b[0], acc[0], 0, 0, 0);
    acc[1] = __builtin_amdgcn_mfma_f32_32x32x16_f16(xf[0], b[4], acc[1], 0, 0, 0);
    acc[0] = __builtin_amdgcn_mfma_f32_32x32x16_f16(xf[1], b[1], acc[0], 0, 0, 0);
    acc[1] = __builtin_amdgcn_mfma_f32_32x32x16_f16(xf[1], b[5], acc[1], 0, 0, 0);
    acc[0] = __builtin_amdgcn_mfma_f32_32x32x16_f16(xf[2], b[2], acc[0], 0, 0, 0);
    acc[1] = __builtin_amdgcn_mfma_f32_32x32x16_f16(xf[2], b[6], acc[1], 0, 0, 0);
    acc[0] = __builtin_amdgcn_mfma_f32_32x32x16_f16(xf[3], b[3], acc[0], 0, 0, 0);
    acc[1] = __builtin_amdgcn_mfma_f32_32x32x16_f16(xf[3], b[7], acc[1], 0, 0, 0);
  };

  // K-loop: 32 positions (c = ks + 2p), 3-buffer rotation, fully static.
  #pragma unroll
  for (int g = 0; g < 10; ++g) {
    COMPUTE(bA, 3 * g);
    if (3 * g + 3 < 32) LOADB(bA, ks + 2 * (3 * g + 3));
    COMPUTE(bB, 3 * g + 1);
    if (3 * g + 4 < 32) LOADB(bB, ks + 2 * (3 * g + 4));
    COMPUTE(bC, 3 * g + 2);
    if (3 * g + 5 < 32)      LOADB(bC, ks + 2 * (3 * g + 5));
    else if (3 * g + 5 == 32 && ks == 0) LOADB(bC, 64);   // bias chunk
  }
  COMPUTE(bA, 30);
  COMPUTE(bB, 31);
  if (ks == 0) COMPUTE_BIAS(bC);

  __syncthreads();   // K-loop done everywhere

  // partials: D row (point) = (r&3)+8*(r>>2)+4*hi, col (o) = ns*32 + r31
  #pragma unroll
  for (int ns = 0; ns < 2; ++ns)
    #pragma unroll
    for (int r = 0; r < 16; ++r) {
      int rowL = mg * 32 + (r & 3) + 8 * (r >> 2) + 4 * hi;
      part[ks][rowL][ns * 32 + r31] = acc[ns][r];
    }
  __syncthreads();

  // reduce 2 partials and store (4 threads/row, 16 cols each)
  {
    int row = tid >> 2;
    int cb  = (tid & 3) * 16;
    float* op = out + (rowblk + row) * 64 + cb;
    #pragma unroll
    for (int j = 0; j < 4; ++j) {
      f32x4 s = *(const f32x4*)(&part[0][row][cb + j * 4]);
      s += *(const f32x4*)(&part[1][row][cb + j * 4]);
      *(f32x4*)(op + j * 4) = s;
    }
  }
}

extern "C" void kernel_launch(void* const* d_in, const int* in_sizes, int n_in,
                              void* d_out, int out_size, void* d_ws, size_t ws_size,
                              hipStream_t stream) {
  const float* x    = (const float*)d_in[0];
  const float* grid = (const float*)d_in[1];
  const float* W1   = (const float*)d_in[2];
  const float* b1   = (const float*)d_in[3];
  const float* W2   = (const float*)d_in[4];
  const float* b2   = (const float*)d_in[5];
  float* out = (float*)d_out;
  _Float16* wsB = (_Float16*)d_ws;   // 65*4096*2 = 532480 bytes

  hipLaunchKernelGGL(prep_kernel, dim3(65), dim3(256), 0, stream,
                     W2, b2, wsB);
  hipLaunchKernelGGL(main_kernel, dim3(N_PTS / ROWS), dim3(256), 0, stream,
                     x, grid, W1, b1, wsB, out);
}